// Round 11
// baseline (115.826 us; speedup 1.0000x reference)
//
#include <hip/hip_runtime.h>
#include <math.h>

#define HDIM 1024
#define VDIM 50257
#define LDIM 512

// block ranges: chain fits in 801 blocks (< 1024 co-resident at 4 blocks/CU)
#define P0_HI 256           // 64 attn blocks (8 rows ea) + 192 gh blocks (16 rows ea)
#define P1_LO 256           // 33 blocks: softmax + ctx(32) / attn-weights out(1)
#define P1_HI 289
#define P2_LO 289           // 256 blocks: combine -> x
#define P2_HI 545
#define P3_LO 545           // 256 blocks: gi + gate -> h_new
#define P3_HI 801
#define MV_LO 801
#define NMV   6283          // ceil(VDIM/8), 8 vocab rows per block
#define GRIDN (MV_LO + NMV)

// ws float offsets
#define WS_FLAG   0         // 4 flag slots as uints at idx 0,16,32,48 (64B apart)
#define WS_ATTLOG 64        // [64,576)
#define WS_CTX    576       // [576,1600)  atomicAdd accum (zeroed by k_zero)
#define WS_X      1600      // [1600,2624)
#define WS_GH     2624      // [2624,5696)
#define WS_HNEW   5696      // [5696,6720)
#define WS_BUCK   6720      // [6720,8768) 128 exp buckets, stride 16 (1/cacheline)

__device__ __forceinline__ float waveSum(float v) {
#pragma unroll
    for (int o = 32; o; o >>= 1) v += __shfl_down(v, o, 64);
    return v;
}

// scalar agent-scope (coherent) access — for small values only
__device__ __forceinline__ void stA(float* p, float v) {
    __hip_atomic_store(p, v, __ATOMIC_RELAXED, __HIP_MEMORY_SCOPE_AGENT);
}
__device__ __forceinline__ float ldA(const float* p) {
    return __hip_atomic_load(p, __ATOMIC_RELAXED, __HIP_MEMORY_SCOPE_AGENT);
}
// coherent VECTOR load: 16B, device-scope (sc0 sc1) — coalesces like a normal
// load but cannot hit a stale per-XCD L2 line. One per thread for bulk staging.
__device__ __forceinline__ float4 ldC4(const float* p) {
    float4 r;
    asm volatile("global_load_dwordx4 %0, %1, off sc0 sc1\n\t"
                 "s_waitcnt vmcnt(0)"
                 : "=v"(r) : "v"(p) : "memory");
    return r;
}

// producer: __syncthreads drains the block's stores, then one relaxed flag add
__device__ __forceinline__ void postF(unsigned* f, int slot) {
    __syncthreads();
    if (threadIdx.x == 0)
        __hip_atomic_fetch_add(f + slot * 16, 1u, __ATOMIC_RELAXED,
                               __HIP_MEMORY_SCOPE_AGENT);
}
// consumer: relaxed polls; data read afterwards via coherent loads (no fence)
template<int SLP>
__device__ __forceinline__ void waitF(unsigned* f, int slot, unsigned tgt, int guard) {
    if (threadIdx.x == 0) {
        unsigned* p = f + slot * 16;
        int g = 0;
        while (__hip_atomic_load(p, __ATOMIC_RELAXED, __HIP_MEMORY_SCOPE_AGENT) < tgt) {
            __builtin_amdgcn_s_sleep(SLP);
            if (++g > guard) break;          // bail instead of hanging harness
        }
    }
    __syncthreads();
}

__global__ __launch_bounds__(256) void k_zero(float* __restrict__ ws) {
    int t = threadIdx.x;
    unsigned* flags = (unsigned*)ws;
    if (t < 64) flags[t] = 0u;
    ws[WS_CTX + t] = 0.f; ws[WS_CTX + 256 + t] = 0.f;
    ws[WS_CTX + 512 + t] = 0.f; ws[WS_CTX + 768 + t] = 0.f;
#pragma unroll
    for (int r = 0; r < 8; ++r) ws[WS_BUCK + r * 256 + t] = 0.f;
}

__global__ __launch_bounds__(256, 4) void k_all(
    const int* __restrict__ idx_p, const float* __restrict__ hidden,
    const float* __restrict__ emb, const float* __restrict__ attn_W,
    const float* __restrict__ attn_b, const float* __restrict__ enc,
    const float* __restrict__ comb_W, const float* __restrict__ comb_b,
    const float* __restrict__ W_ih, const float* __restrict__ W_hh,
    const float* __restrict__ b_ih, const float* __restrict__ b_hh,
    const float* __restrict__ out_W, const float* __restrict__ out_b,
    float* __restrict__ ws, float* __restrict__ out)
{
    const int blk = blockIdx.x, t = threadIdx.x;
    const int wid = t >> 6, lane = t & 63;
    __shared__ __align__(16) float sbuf[1024];
    __shared__ float sred[4];
    __shared__ float se[4];
    unsigned* flags = (unsigned*)ws;
    const float4* h4 = (const float4*)hidden;

    if (blk < 64) {
        // ---- P0a: attention logits, 8 rows/block (2 per wave) ----
        const float4* e4 = (const float4*)(emb + (size_t)idx_p[0] * HDIM);
        int r0 = blk * 8 + wid * 2;
        const float4* wa = (const float4*)(attn_W + (size_t)r0 * 2 * HDIM);
        const float4* wb = wa + 512;
        float acc0 = 0.f, acc1 = 0.f;
#pragma unroll
        for (int k = 0; k < 8; ++k) {
            int c = lane + 64 * k;
            float4 x = (c < 256) ? e4[c] : h4[c - 256];
            float4 a = wa[c], b = wb[c];
            acc0 += a.x * x.x + a.y * x.y + a.z * x.z + a.w * x.w;
            acc1 += b.x * x.x + b.y * x.y + b.z * x.z + b.w * x.w;
        }
        acc0 = waveSum(acc0); acc1 = waveSum(acc1);
        if (lane == 0) {
            stA(ws + WS_ATTLOG + r0,     acc0 + attn_b[r0]);
            stA(ws + WS_ATTLOG + r0 + 1, acc1 + attn_b[r0 + 1]);
        }
        postF(flags, 0);
    } else if (blk < P0_HI) {
        // ---- P0b: gh = h@W_hh.T + b_hh, 16 rows/block (4 per wave) ----
        int r0 = (blk - 64) * 16 + wid * 4;
        const float* wbase = W_hh + (size_t)r0 * HDIM;
        float a0 = 0.f, a1 = 0.f, a2 = 0.f, a3 = 0.f;
#pragma unroll
        for (int q = 0; q < 4; ++q) {
            int c = lane + 64 * q;
            float4 x = h4[c];
            float4 w0 = ((const float4*)(wbase))[c];
            float4 w1 = ((const float4*)(wbase + HDIM))[c];
            float4 w2 = ((const float4*)(wbase + 2 * HDIM))[c];
            float4 w3 = ((const float4*)(wbase + 3 * HDIM))[c];
            a0 += w0.x * x.x + w0.y * x.y + w0.z * x.z + w0.w * x.w;
            a1 += w1.x * x.x + w1.y * x.y + w1.z * x.z + w1.w * x.w;
            a2 += w2.x * x.x + w2.y * x.y + w2.z * x.z + w2.w * x.w;
            a3 += w3.x * x.x + w3.y * x.y + w3.z * x.z + w3.w * x.w;
        }
        a0 = waveSum(a0); a1 = waveSum(a1); a2 = waveSum(a2); a3 = waveSum(a3);
        if (lane == 0) {
            stA(ws + WS_GH + r0,     a0 + b_hh[r0]);
            stA(ws + WS_GH + r0 + 1, a1 + b_hh[r0 + 1]);
            stA(ws + WS_GH + r0 + 2, a2 + b_hh[r0 + 2]);
            stA(ws + WS_GH + r0 + 3, a3 + b_hh[r0 + 3]);
        }
        postF(flags, 0);
    } else if (blk < P1_HI) {
        // ---- P1: redundant softmax(512); ctx slice or attn-weight output ----
        waitF<2>(flags, 0, P0_HI, 1000000);
        int b = blk - P1_LO;
        float v0 = ldA(ws + WS_ATTLOG + t), v1 = ldA(ws + WS_ATTLOG + 256 + t);
        float m = fmaxf(v0, v1);
#pragma unroll
        for (int o = 32; o; o >>= 1) m = fmaxf(m, __shfl_down(m, o, 64));
        if (lane == 0) sred[wid] = m;
        __syncthreads();
        m = fmaxf(fmaxf(sred[0], sred[1]), fmaxf(sred[2], sred[3]));
        __syncthreads();
        float e0 = expf(v0 - m), e1 = expf(v1 - m);
        float s = waveSum(e0 + e1);
        if (lane == 0) sred[wid] = s;
        __syncthreads();
        s = sred[0] + sred[1] + sred[2] + sred[3];
        float inv = 1.f / s;
        sbuf[t] = e0 * inv; sbuf[256 + t] = e1 * inv;
        __syncthreads();
        if (b == 32) {
            out[VDIM + HDIM + t] = sbuf[t];
            out[VDIM + HDIM + 256 + t] = sbuf[256 + t];
        } else {
            int lc = b & 7, hb = b >> 3;            // 8 L-chunks x 4 H-chunks
            int h = hb * 256 + t;
            int l0 = lc * 64;
            float acc = 0.f;
#pragma unroll 8
            for (int j = 0; j < 64; ++j)
                acc += sbuf[l0 + j] * enc[(size_t)(l0 + j) * HDIM + h];
            atomicAdd(&ws[WS_CTX + h], acc);        // device-scope, 1024 spread addrs
            postF(flags, 1);
        }
    } else if (blk < P2_HI) {
        // ---- P2: combine -> x ----
        waitF<2>(flags, 1, 32, 1000000);
        ((float4*)sbuf)[t] = ldC4(ws + WS_CTX + 4 * t);   // one coherent 16B/thread
        __syncthreads();
        const float4* s4 = (const float4*)sbuf;
        const float4* e4 = (const float4*)(emb + (size_t)idx_p[0] * HDIM);
        int j = (blk - P2_LO) * 4 + wid;            // 0..1023
        const float4* w4 = (const float4*)(comb_W + (size_t)j * 2 * HDIM);
        float acc = 0.f;
#pragma unroll
        for (int k = 0; k < 8; ++k) {
            int c = lane + 64 * k;
            float4 w = w4[c];
            float4 x = (c < 256) ? e4[c] : s4[c - 256];
            acc += w.x * x.x + w.y * x.y + w.z * x.z + w.w * x.w;
        }
        acc = waveSum(acc);
        if (lane == 0) stA(ws + WS_X + j, fmaxf(acc + comb_b[j], 0.f));
        postF(flags, 2);
    } else if (blk < P3_HI) {
        // ---- P3: gi + GRU gate -> h_new (wave per h-index) ----
        waitF<2>(flags, 2, P2_HI - P2_LO, 1000000);
        ((float4*)sbuf)[t] = ldC4(ws + WS_X + 4 * t);
        __syncthreads();
        const float4* s4 = (const float4*)sbuf;
        int i = (blk - P3_LO) * 4 + wid;            // 0..1023
        const float4* wr = (const float4*)(W_ih + (size_t)i * HDIM);
        const float4* wz = (const float4*)(W_ih + (size_t)(HDIM + i) * HDIM);
        const float4* wn = (const float4*)(W_ih + (size_t)(2 * HDIM + i) * HDIM);
        float a0 = 0.f, a1 = 0.f, a2 = 0.f;
#pragma unroll
        for (int q = 0; q < 4; ++q) {
            int c = lane + 64 * q;
            float4 x = s4[c];
            float4 w0 = wr[c], w1 = wz[c], w2 = wn[c];
            a0 += w0.x * x.x + w0.y * x.y + w0.z * x.z + w0.w * x.w;
            a1 += w1.x * x.x + w1.y * x.y + w1.z * x.z + w1.w * x.w;
            a2 += w2.x * x.x + w2.y * x.y + w2.z * x.z + w2.w * x.w;
        }
        a0 = waveSum(a0); a1 = waveSum(a1); a2 = waveSum(a2);
        if (lane == 0) {
            float gi_r = a0 + b_ih[i];
            float gi_z = a1 + b_ih[HDIM + i];
            float gi_n = a2 + b_ih[2 * HDIM + i];
            float gh_r = ldA(ws + WS_GH + i);
            float gh_z = ldA(ws + WS_GH + HDIM + i);
            float gh_n = ldA(ws + WS_GH + 2 * HDIM + i);
            float r_ = 1.f / (1.f + expf(-(gi_r + gh_r)));
            float z  = 1.f / (1.f + expf(-(gi_z + gh_z)));
            float n  = tanhf(gi_n + r_ * gh_n);
            float hn = (1.f - z) * n + z * hidden[i];
            stA(ws + WS_HNEW + i, hn);
            out[VDIM + i] = hn;
        }
        postF(flags, 3);
    } else {
        // ---- MV: V-matvec, 8 rows/block (2 per wave) ----
        waitF<16>(flags, 3, P3_HI - P3_LO, 200000);
        ((float4*)sbuf)[t] = ldC4(ws + WS_HNEW + 4 * t);  // one coherent 16B/thread
        __syncthreads();
        const float4* s4 = (const float4*)sbuf;
        int mb = blk - MV_LO;
        int v0 = mb * 8 + wid * 2, v1 = v0 + 1;
        int va = v0 < VDIM ? v0 : 0, vb = v1 < VDIM ? v1 : 0;
        const float4* wa = (const float4*)(out_W + (size_t)va * HDIM);
        const float4* wb = (const float4*)(out_W + (size_t)vb * HDIM);
        float4 x0 = s4[lane], x1 = s4[lane + 64], x2 = s4[lane + 128], x3 = s4[lane + 192];
        float4 a0 = wa[lane], a1 = wa[lane + 64], a2 = wa[lane + 128], a3 = wa[lane + 192];
        float4 b0 = wb[lane], b1 = wb[lane + 64], b2 = wb[lane + 128], b3 = wb[lane + 192];
        float acc0 = a0.x * x0.x + a0.y * x0.y + a0.z * x0.z + a0.w * x0.w
                   + a1.x * x1.x + a1.y * x1.y + a1.z * x1.z + a1.w * x1.w
                   + a2.x * x2.x + a2.y * x2.y + a2.z * x2.z + a2.w * x2.w
                   + a3.x * x3.x + a3.y * x3.y + a3.z * x3.z + a3.w * x3.w;
        float acc1 = b0.x * x0.x + b0.y * x0.y + b0.z * x0.z + b0.w * x0.w
                   + b1.x * x1.x + b1.y * x1.y + b1.z * x1.z + b1.w * x1.w
                   + b2.x * x2.x + b2.y * x2.y + b2.z * x2.z + b2.w * x2.w
                   + b3.x * x3.x + b3.y * x3.y + b3.z * x3.z + b3.w * x3.w;
        acc0 = waveSum(acc0); acc1 = waveSum(acc1);
        if (lane == 0) {
            float ep = 0.f;
            if (v0 < VDIM) { float l0 = acc0 + out_b[v0]; out[v0] = l0; ep += expf(l0); }
            if (v1 < VDIM) { float l1 = acc1 + out_b[v1]; out[v1] = l1; ep += expf(l1); }
            se[wid] = ep;
        }
        __syncthreads();
        if (t == 0)
            atomicAdd(&ws[WS_BUCK + (blk & 127) * 16],
                      se[0] + se[1] + se[2] + se[3]);
    }
}

// K6: out[i] -= log(sum of 128 strided buckets)
__global__ __launch_bounds__(256) void k6(const float* __restrict__ ws,
                                          float* __restrict__ out) {
    __shared__ float sls[2];
    const int t = threadIdx.x, wid = t >> 6, lane = t & 63;
    if (t < 128) {
        float b = waveSum(ws[WS_BUCK + t * 16]);
        if (lane == 0) sls[wid] = b;
    }
    __syncthreads();
    float ls = logf(sls[0] + sls[1]);
    int i = blockIdx.x * 256 + t;
    if (i < VDIM) out[i] -= ls;
}

extern "C" void kernel_launch(void* const* d_in, const int* in_sizes, int n_in,
                              void* d_out, int out_size, void* d_ws, size_t ws_size,
                              hipStream_t stream) {
    const int*   idx    = (const int*)d_in[0];
    const float* hidden = (const float*)d_in[1];
    const float* enc    = (const float*)d_in[2];
    const float* emb    = (const float*)d_in[3];
    const float* attn_W = (const float*)d_in[4];
    const float* attn_b = (const float*)d_in[5];
    const float* comb_W = (const float*)d_in[6];
    const float* comb_b = (const float*)d_in[7];
    const float* W_ih   = (const float*)d_in[8];
    const float* W_hh   = (const float*)d_in[9];
    const float* b_ih   = (const float*)d_in[10];
    const float* b_hh   = (const float*)d_in[11];
    const float* out_W  = (const float*)d_in[12];
    const float* out_b  = (const float*)d_in[13];

    float* out = (float*)d_out;                 // [V logits][H h_new][L attn_w]
    float* ws  = (float*)d_ws;

    k_zero<<<1, 256, 0, stream>>>(ws);
    k_all<<<GRIDN, 256, 0, stream>>>(idx, hidden, emb, attn_W, attn_b, enc,
                                     comb_W, comb_b, W_ih, W_hh, b_ih, b_hh,
                                     out_W, out_b, ws, out);
    k6<<<(VDIM + 255) / 256, 256, 0, stream>>>(ws, out);
}

// Round 12
// 56.836 us; speedup vs baseline: 2.0379x; 2.0379x over previous
//
#include <hip/hip_runtime.h>
#include <math.h>

#define HDIM 1024
#define VDIM 50257
#define LDIM 512

// ws float offsets (all 16B-aligned)
#define WS_ATTLOG 0      // [0,512)       attention logits
#define WS_CTXP   512    // [512,8704)    ctx partials [8][1024] (plain stores)
#define WS_X      8704   // [8704,9728)   GRU input x
#define WS_GH     9728   // [9728,12800)  gh = h@W_hh.T + b_hh
#define WS_HNEW   12800  // [12800,13824) h_new
#define WS_BUCK   13824  // [13824,15872) 128 exp-sum buckets, stride 16 (1/cacheline)

__device__ __forceinline__ float waveSum(float v) {
#pragma unroll
    for (int o = 32; o; o >>= 1) v += __shfl_down(v, o, 64);
    return v;
}

// K1: attn logits (blocks 0..127) + gh rows (blocks 128..895); block 0 zeros buckets
__global__ __launch_bounds__(256) void k1(const int* __restrict__ idx_p,
                                          const float* __restrict__ hidden,
                                          const float* __restrict__ emb,
                                          const float* __restrict__ attn_W,
                                          const float* __restrict__ attn_b,
                                          const float* __restrict__ W_hh,
                                          const float* __restrict__ b_hh,
                                          float* __restrict__ ws) {
    const int blk = blockIdx.x, t = threadIdx.x;
    const int wid = t >> 6, lane = t & 63;
    if (blk == 0) {
#pragma unroll
        for (int r = 0; r < 8; ++r) ws[WS_BUCK + r * 256 + t] = 0.f;
    }
    const float4* h4 = (const float4*)hidden;
    if (blk < 128) {
        const float4* e4 = (const float4*)(emb + (size_t)idx_p[0] * HDIM);
        int row = blk * 4 + wid;                        // 0..511
        const float4* w4 = (const float4*)(attn_W + (size_t)row * 2 * HDIM);
        float acc = 0.f;
#pragma unroll
        for (int k = 0; k < 8; ++k) {
            int c = lane + 64 * k;                      // float4 chunk 0..511
            float4 w = w4[c];
            float4 x = (c < 256) ? e4[c] : h4[c - 256];
            acc += w.x * x.x + w.y * x.y + w.z * x.z + w.w * x.w;
        }
        acc = waveSum(acc);
        if (lane == 0) ws[WS_ATTLOG + row] = acc + attn_b[row];
    } else {
        int k = (blk - 128) * 4 + wid;                  // 0..3071
        const float4* w4 = (const float4*)(W_hh + (size_t)k * HDIM);
        float acc = 0.f;
#pragma unroll
        for (int q = 0; q < 4; ++q) {
            int c = lane + 64 * q;
            float4 w = w4[c]; float4 x = h4[c];
            acc += w.x * x.x + w.y * x.y + w.z * x.z + w.w * x.w;
        }
        acc = waveSum(acc);
        if (lane == 0) ws[WS_GH + k] = acc + b_hh[k];
    }
}

// K2: redundant softmax(512) per block; blocks 0..31: ctx partial (64 L-rows x 256 h,
//     plain store); block 32: attention-weights output. No atomics.
__global__ __launch_bounds__(256) void k2(const float* __restrict__ enc,
                                          float* __restrict__ ws,
                                          float* __restrict__ out) {
    __shared__ float sred[4];
    __shared__ float sW[512];
    const int blk = blockIdx.x, t = threadIdx.x;
    const int wid = t >> 6, lane = t & 63;
    float v0 = ws[WS_ATTLOG + t], v1 = ws[WS_ATTLOG + 256 + t];
    float m = fmaxf(v0, v1);
#pragma unroll
    for (int o = 32; o; o >>= 1) m = fmaxf(m, __shfl_down(m, o, 64));
    if (lane == 0) sred[wid] = m;
    __syncthreads();
    m = fmaxf(fmaxf(sred[0], sred[1]), fmaxf(sred[2], sred[3]));
    __syncthreads();
    float e0 = expf(v0 - m), e1 = expf(v1 - m);
    float s = waveSum(e0 + e1);
    if (lane == 0) sred[wid] = s;
    __syncthreads();
    s = sred[0] + sred[1] + sred[2] + sred[3];
    float inv = 1.f / s;
    sW[t] = e0 * inv; sW[256 + t] = e1 * inv;
    __syncthreads();
    if (blk == 32) {
        out[VDIM + HDIM + t] = sW[t];
        out[VDIM + HDIM + 256 + t] = sW[256 + t];
    } else {
        int lc = blk & 7, hb = blk >> 3;                // 8 L-chunks x 4 H-chunks
        int h = hb * 256 + t;
        int l0 = lc * 64;
        float acc = 0.f;
#pragma unroll 8
        for (int j = 0; j < 64; ++j)
            acc += sW[l0 + j] * enc[(size_t)(l0 + j) * HDIM + h];
        ws[WS_CTXP + lc * HDIM + h] = acc;              // plain store
    }
}

// K3: sum 8 ctx partials into LDS, then x[j] = relu(dot(cat(emb,ctx), comb_W[j]) + b)
__global__ __launch_bounds__(256) void k3(const int* __restrict__ idx_p,
                                          const float* __restrict__ emb,
                                          const float* __restrict__ comb_W,
                                          const float* __restrict__ comb_b,
                                          float* __restrict__ ws) {
    __shared__ __align__(16) float sctx[1024];
    const int t = threadIdx.x, wid = t >> 6, lane = t & 63;
    {   // thread t sums partials for float4 chunk t (h = 4t..4t+3)
        const float4* p4 = (const float4*)(ws + WS_CTXP);
        float4 a = p4[t];
#pragma unroll
        for (int p = 1; p < 8; ++p) {
            float4 b = p4[p * 256 + t];
            a.x += b.x; a.y += b.y; a.z += b.z; a.w += b.w;
        }
        ((float4*)sctx)[t] = a;
    }
    __syncthreads();
    int j = blockIdx.x * 4 + wid;                       // 0..1023
    const float4* w4 = (const float4*)(comb_W + (size_t)j * 2 * HDIM);
    const float4* e4 = (const float4*)(emb + (size_t)idx_p[0] * HDIM);
    const float4* c4 = (const float4*)sctx;
    float acc = 0.f;
#pragma unroll
    for (int k = 0; k < 8; ++k) {
        int c = lane + 64 * k;
        float4 w = w4[c];
        float4 x = (c < 256) ? e4[c] : c4[c - 256];
        acc += w.x * x.x + w.y * x.y + w.z * x.z + w.w * x.w;
    }
    acc = waveSum(acc);
    if (lane == 0) ws[WS_X + j] = fmaxf(acc + comb_b[j], 0.f);
}

// K4: gi + GRU gate, one h-index per 192-thread block (3 waves = 3 gate rows).
__global__ __launch_bounds__(192) void k4(const float* __restrict__ hidden,
                                          const float* __restrict__ W_ih,
                                          const float* __restrict__ b_ih,
                                          float* __restrict__ ws,
                                          float* __restrict__ out) {
    __shared__ float sg[3];
    const int i = blockIdx.x;                           // h index 0..1023
    const int t = threadIdx.x, r = t >> 6, lane = t & 63;
    const float4* w4 = (const float4*)(W_ih + (size_t)(r * HDIM + i) * HDIM);
    const float4* x4 = (const float4*)(ws + WS_X);
    float acc = 0.f;
#pragma unroll
    for (int q = 0; q < 4; ++q) {
        int c = lane + 64 * q;
        float4 w = w4[c]; float4 x = x4[c];
        acc += w.x * x.x + w.y * x.y + w.z * x.z + w.w * x.w;
    }
    acc = waveSum(acc);
    if (lane == 0) sg[r] = acc + b_ih[r * HDIM + i];
    __syncthreads();
    if (t == 0) {
        float gh_r = ws[WS_GH + i];
        float gh_z = ws[WS_GH + HDIM + i];
        float gh_n = ws[WS_GH + 2 * HDIM + i];
        float r_ = 1.f / (1.f + expf(-(sg[0] + gh_r)));
        float z  = 1.f / (1.f + expf(-(sg[1] + gh_z)));
        float n  = tanhf(sg[2] + r_ * gh_n);
        float hn = (1.f - z) * n + z * hidden[i];
        ws[WS_HNEW + i] = hn;
        out[VDIM + i]   = hn;
    }
}

// K5: V-matvec (one vocab row per wave) + per-block exp partial into a
//     cacheline-private bucket (128 buckets, stride 16 floats).
__global__ __launch_bounds__(256) void k5(const float* __restrict__ out_W,
                                          const float* __restrict__ out_b,
                                          float* __restrict__ ws,
                                          float* __restrict__ out) {
    __shared__ float se[4];
    const int t = threadIdx.x, wid = t >> 6, lane = t & 63;
    int v = blockIdx.x * 4 + wid;
    const float4* h4 = (const float4*)(ws + WS_HNEW);
    if (v < VDIM) {
        const float4* w4 = (const float4*)(out_W + (size_t)v * HDIM);
        float acc = 0.f;
#pragma unroll
        for (int q = 0; q < 4; ++q) {
            int c = lane + 64 * q;
            float4 w = w4[c]; float4 x = h4[c];
            acc += w.x * x.x + w.y * x.y + w.z * x.z + w.w * x.w;
        }
        acc = waveSum(acc);
        if (lane == 0) {
            float logit = acc + out_b[v];
            out[v] = logit;
            se[wid] = expf(logit);
        }
    } else if (lane == 0) {
        se[wid] = 0.f;
    }
    __syncthreads();
    if (t == 0)
        atomicAdd(&ws[WS_BUCK + (blockIdx.x & 127) * 16],
                  se[0] + se[1] + se[2] + se[3]);
}

// K6: out[i] -= log(sum of 128 strided buckets)
__global__ __launch_bounds__(256) void k6(const float* __restrict__ ws,
                                          float* __restrict__ out) {
    __shared__ float sls[2];
    const int t = threadIdx.x, wid = t >> 6, lane = t & 63;
    if (t < 128) {
        float b = waveSum(ws[WS_BUCK + t * 16]);
        if (lane == 0) sls[wid] = b;
    }
    __syncthreads();
    float ls = logf(sls[0] + sls[1]);
    int i = blockIdx.x * 256 + t;
    if (i < VDIM) out[i] -= ls;
}

extern "C" void kernel_launch(void* const* d_in, const int* in_sizes, int n_in,
                              void* d_out, int out_size, void* d_ws, size_t ws_size,
                              hipStream_t stream) {
    const int*   idx    = (const int*)d_in[0];
    const float* hidden = (const float*)d_in[1];
    const float* enc    = (const float*)d_in[2];
    const float* emb    = (const float*)d_in[3];
    const float* attn_W = (const float*)d_in[4];
    const float* attn_b = (const float*)d_in[5];
    const float* comb_W = (const float*)d_in[6];
    const float* comb_b = (const float*)d_in[7];
    const float* W_ih   = (const float*)d_in[8];
    const float* W_hh   = (const float*)d_in[9];
    const float* b_ih   = (const float*)d_in[10];
    const float* b_hh   = (const float*)d_in[11];
    const float* out_W  = (const float*)d_in[12];
    const float* out_b  = (const float*)d_in[13];

    float* out = (float*)d_out;                 // [V logits][H h_new][L attn_w]
    float* ws  = (float*)d_ws;

    k1<<<896, 256, 0, stream>>>(idx, hidden, emb, attn_W, attn_b, W_hh, b_hh, ws);
    k2<<<33, 256, 0, stream>>>(enc, ws, out);
    k3<<<256, 256, 0, stream>>>(idx, emb, comb_W, comb_b, ws);
    k4<<<1024, 192, 0, stream>>>(hidden, W_ih, b_ih, ws, out);
    k5<<<(VDIM + 3) / 4, 256, 0, stream>>>(out_W, out_b, ws, out);
    k6<<<(VDIM + 255) / 256, 256, 0, stream>>>(ws, out);
}